// Round 9
// baseline (631.491 us; speedup 1.0000x reference)
//
#include <hip/hip_runtime.h>
#include <hip/hip_bf16.h>
#include <stdint.h>

#define B_ROWS 4096
#define HD 1024
#define IN_DIM 784
#define IN_PAD 832
#define T_TICKS 32

typedef float f32x4 __attribute__((ext_vector_type(4)));
typedef short short8 __attribute__((ext_vector_type(8)));
typedef __hip_bfloat16 bf16;

// LDS: 2 A-buffers x 8KB (64 rows x 128B, XOR-swizzled via pre-swizzled source)
#define ABUF 8192

__device__ __forceinline__ float b2f(short s) {
  unsigned u = ((unsigned)(unsigned short)s) << 16;
  float f; __builtin_memcpy(&f, &u, 4); return f;
}

__device__ __forceinline__ float softplus_f(float x) {
  if (x > 20.f) return x;
  return log1pf(expf(x));
}

__device__ __forceinline__ float tanh_fast(float x) {
  x = fminf(fmaxf(x, -15.f), 15.f);
  float e = __expf(2.f * x);
  return (e - 1.f) / (e + 1.f);
}

__device__ __forceinline__ void gload_lds16(const void* g, void* l) {
  __builtin_amdgcn_global_load_lds(
      (const __attribute__((address_space(1))) uint32_t*)g,
      (__attribute__((address_space(3))) uint32_t*)l, 16, 0, 0);
}

// ---------- f32 -> bf16 with zero-pad of inner dim ----------
__global__ __launch_bounds__(256) void conv_pad_kernel(
    const float* __restrict__ src, bf16* __restrict__ dst,
    int rows, int scols, int dcols) {
  int idx = blockIdx.x * 256 + threadIdx.x;
  int total = rows * dcols;
  if (idx >= total) return;
  int r = idx / dcols, c = idx - r * dcols;
  float v = (c < scols) ? src[(size_t)r * scols + c] : 0.f;
  dst[idx] = __float2bfloat16(v);
}

// ---------- pack weight (1024 x scols f32) into MFMA B-fragment order ----------
// frag f = ((wnny*nkt + kt)*2 + ks)*4 + n ; each frag = 64 lanes x 16B = 1024B.
// lane(r=lane&15,q=lane>>4): row = wnny*64 + n*16 + r ; k = kt*64 + ks*32 + q*8 .. +8
__global__ __launch_bounds__(256) void pack_w(
    const float* __restrict__ src, bf16* __restrict__ dst,
    int nkt, int scols) {
  int gid = blockIdx.x * 256 + threadIdx.x;
  int lane = gid & 63, f = gid >> 6;
  int total = 16 * nkt * 2 * 4;
  if (f >= total) return;
  int n = f & 3;
  int rest = f >> 2;
  int ks = rest & 1;
  int rest2 = rest >> 1;
  int kt = rest2 % nkt;
  int wnny = rest2 / nkt;
  int r = lane & 15, q = lane >> 4;
  int row = wnny * 64 + n * 16 + r;
  int k0 = kt * 64 + ks * 32 + q * 8;
  short8 v;
#pragma unroll
  for (int e = 0; e < 8; ++e) {
    int c = k0 + e;
    float x = (c < scols) ? src[(size_t)row * scols + c] : 0.f;
    bf16 b = __float2bfloat16(x);
    v[e] = *(short*)&b;
  }
  *(short8*)((char*)dst + (size_t)f * 1024 + lane * 16) = v;
}

// ---------- pack fe_W (5 x 1024 f32 -> 16 padded rows) into fragments ----------
// frag f = kt*2+ks (kt<16); lane(r,q): row=r (zero if >=5), k = kt*64+ks*32+q*8
__global__ __launch_bounds__(256) void pack_fe(
    const float* __restrict__ feW, bf16* __restrict__ dst) {
  int gid = blockIdx.x * 256 + threadIdx.x;
  int lane = gid & 63, f = gid >> 6;
  if (f >= 32) return;
  int ks = f & 1, kt = f >> 1;
  int r = lane & 15, q = lane >> 4;
  int k0 = kt * 64 + ks * 32 + q * 8;
  short8 v;
#pragma unroll
  for (int e = 0; e < 8; ++e) {
    float x = (r < 5) ? feW[(size_t)r * HD + k0 + e] : 0.f;
    bf16 b = __float2bfloat16(x);
    v[e] = *(short*)&b;
  }
  *(short8*)((char*)dst + (size_t)f * 1024 + lane * 16) = v;
}

// ---------- GEMM C = A * B^T, packed-B in registers, A via global_load_lds ----------
// BM=64, BN=128, BK=64, 256 threads (4 waves 2x2, wave tile 32x64). Grid 512.
// Sync: ONLY __syncthreads() per K-step (full drain; proven R2 combo).
// MODE 0: xp_out = bf16(acc + bias1 + bias2)
// MODE 1: outH = bf16(tanh(acc + xp)); fe fused on wave0 of ny<4 blocks.
template<int KDIM, int MODE>
__global__ __launch_bounds__(256) void gemm_core(
    const bf16* __restrict__ A,
    const bf16* __restrict__ Bpk,        // packed B fragments
    const bf16* __restrict__ feP,        // packed fe fragments (MODE 1)
    const float* __restrict__ bias1, const float* __restrict__ bias2,
    const bf16* __restrict__ xp, bf16* __restrict__ xp_out,
    bf16* __restrict__ outH, float* __restrict__ feRaw, int tprev)
{
  __shared__ char lds[2 * ABUF];
  const int tid = threadIdx.x;
  const int lane = tid & 63, w = tid >> 6;
  const int wm = w & 1, wn = w >> 1;
  const int l3 = lane >> 3, l7 = lane & 7;
  const int gcol = l7 ^ l3;               // inverse-swizzled source chunk
  const int r = lane & 15, q = lane >> 4;
  const int r7 = r & 7;
  const int lane16 = lane * 16;
  const int ldaB = KDIM * 2;
  const int NK = KDIM / 64;

  // XCD-chunked bijective swizzle: nwg = 512, 64 per XCD (8 mx x 8 ny)
  int bid = blockIdx.x;
  int v = (bid & 7) * 64 + (bid >> 3);
  const int mx = v >> 3, ny = v & 7;
  const int bm0 = mx * 64, bn0 = ny * 128;

  const bool feW0 = (MODE == 1) && (ny < 4) && (w == 0);

  f32x4 acc[2][4] = {};
  f32x4 acc_fe = {};

  const char* Asrc = (const char*)A + (size_t)(bm0 + l3) * ldaB + gcol * 16;
  const char* Bkt  = (const char*)Bpk + (size_t)(ny * 2 + wn) * NK * 8192;

  short8 Be[8], Bo[8], Bef[2], Bof[2];

#define STAGEA(buf, k)                                                         \
  {                                                                            \
    const char* Ak = Asrc + (size_t)(k) * 128;                                 \
    _Pragma("unroll") for (int j = 0; j < 2; ++j) {                            \
      int iA = w * 2 + j;                                                      \
      gload_lds16(Ak + (size_t)iA * 8 * ldaB, lds + (buf) * ABUF + iA * 1024); \
    }                                                                          \
  }

#define ISSUEB(BS, BSf, k)                                                     \
  {                                                                            \
    const char* bp = Bkt + (size_t)(k) * 8192;                                 \
    _Pragma("unroll") for (int i = 0; i < 8; ++i)                              \
      BS[i] = *(const short8*)(bp + i * 1024 + lane16);                        \
    if (feW0) {                                                                \
      const char* fp = (const char*)feP + (size_t)(k) * 2048;                  \
      BSf[0] = *(const short8*)(fp + lane16);                                  \
      BSf[1] = *(const short8*)(fp + 1024 + lane16);                           \
    }                                                                          \
  }

#define ITER(kp, BS, BSf)                                                      \
  {                                                                            \
    const int _k = (kp);                                                       \
    if (_k + 1 < NK) STAGEA((_k + 1) & 1, _k + 1);                             \
    const char* lAb = lds + (_k & 1) * ABUF;                                   \
    short8 af[2][2], af_fe[2];                                                 \
    _Pragma("unroll") for (int ks = 0; ks < 2; ++ks) {                         \
      int sw = ((ks * 4 + q) ^ r7) << 4;                                       \
      _Pragma("unroll") for (int m = 0; m < 2; ++m)                            \
        af[ks][m] = *(const short8*)(lAb + (wm * 32 + m * 16 + r) * 128 + sw); \
    }                                                                          \
    if (feW0) {                                                                \
      _Pragma("unroll") for (int ks = 0; ks < 2; ++ks) {                       \
        int sw = ((ks * 4 + q) ^ r7) << 4;                                     \
        af_fe[ks] = *(const short8*)(lAb + (ny * 16 + r) * 128 + sw);          \
      }                                                                        \
    }                                                                          \
    _Pragma("unroll") for (int ks = 0; ks < 2; ++ks)                           \
      _Pragma("unroll") for (int m = 0; m < 2; ++m)                            \
        _Pragma("unroll") for (int n = 0; n < 4; ++n)                          \
          acc[m][n] = __builtin_amdgcn_mfma_f32_16x16x32_bf16(                 \
              af[ks][m], BS[ks * 4 + n], acc[m][n], 0, 0, 0);                  \
    if (feW0) {                                                                \
      acc_fe = __builtin_amdgcn_mfma_f32_16x16x32_bf16(af_fe[0], BSf[0], acc_fe, 0, 0, 0); \
      acc_fe = __builtin_amdgcn_mfma_f32_16x16x32_bf16(af_fe[1], BSf[1], acc_fe, 0, 0, 0); \
    }                                                                          \
    if (_k + 2 < NK) ISSUEB(BS, BSf, _k + 2);                                  \
    __syncthreads();                                                           \
  }

  // prologue: stage tile 0 into buf0; B sets for tiles 0,1 in flight
  STAGEA(0, 0);
  ISSUEB(Be, Bef, 0);
  ISSUEB(Bo, Bof, 1);
  __syncthreads();

#pragma unroll
  for (int kt = 0; kt + 1 < NK; kt += 2) {
    ITER(kt,     Be, Bef);   // even tiles in Be
    ITER(kt + 1, Bo, Bof);   // odd tiles in Bo
  }
  if (NK & 1) {
    ITER(NK - 1, Be, Bef);
  }
#undef ITER
#undef ISSUEB
#undef STAGEA

#pragma unroll
  for (int m = 0; m < 2; ++m) {
#pragma unroll
    for (int n = 0; n < 4; ++n) {
      int col = bn0 + wn * 64 + n * 16 + r;
#pragma unroll
      for (int i = 0; i < 4; ++i) {
        int row = bm0 + wm * 32 + m * 16 + q * 4 + i;
        float vv = acc[m][n][i];
        if (MODE == 0) {
          xp_out[(size_t)row * HD + col] = __float2bfloat16(vv + bias1[col] + bias2[col]);
        } else {
          float val = tanh_fast(vv + b2f(*(const short*)&xp[(size_t)row * HD + col]));
          outH[(size_t)row * HD + col] = __float2bfloat16(val);
        }
      }
    }
  }
  if (feW0 && tprev >= 0 && r < 5) {
#pragma unroll
    for (int i = 0; i < 4; ++i) {
      int rowg = bm0 + ny * 16 + q * 4 + i;
      feRaw[((size_t)rowg * T_TICKS + tprev) * 5 + r] = acc_fe[i];
    }
  }
}

// ---------- fe for the last tick: one wave per row, 5 raw dots ----------
__global__ __launch_bounds__(256) void fe_last(
    const bf16* __restrict__ h, const float* __restrict__ feW,
    float* __restrict__ feRaw)
{
  int wid = threadIdx.x >> 6, lane = threadIdx.x & 63;
  int b = blockIdx.x * 4 + wid;
  const bf16* hr = h + (size_t)b * HD + lane * 16;
  short8 hv0 = *(const short8*)hr;
  short8 hv1 = *(const short8*)(hr + 8);
  float hvf[16];
#pragma unroll
  for (int e = 0; e < 8; ++e) { hvf[e] = b2f(hv0[e]); hvf[8 + e] = b2f(hv1[e]); }

  float a0 = 0, a1 = 0, a2 = 0, a3 = 0, a4 = 0;
  int col0 = lane * 16;
#pragma unroll
  for (int e = 0; e < 16; ++e) {
    float hv = hvf[e];
    int col = col0 + e;
    a0 += hv * feW[0 * HD + col];
    a1 += hv * feW[1 * HD + col];
    a2 += hv * feW[2 * HD + col];
    a3 += hv * feW[3 * HD + col];
    a4 += hv * feW[4 * HD + col];
  }
#pragma unroll
  for (int off = 32; off >= 1; off >>= 1) {
    a0 += __shfl_xor(a0, off);
    a1 += __shfl_xor(a1, off);
    a2 += __shfl_xor(a2, off);
    a3 += __shfl_xor(a3, off);
    a4 += __shfl_xor(a4, off);
  }
  if (lane == 0) {
    float* fr = feRaw + ((size_t)b * T_TICKS + (T_TICKS - 1)) * 5;
    fr[0] = a0; fr[1] = a1; fr[2] = a2; fr[3] = a3; fr[4] = a4;
  }
}

// ---------- finish: softplus / z / L for all (b,t) ----------
__global__ __launch_bounds__(256) void finish_kernel(
    const float* __restrict__ feRaw, const float* __restrict__ feB,
    const float* __restrict__ eps, float* __restrict__ out)
{
  int gid = blockIdx.x * 256 + threadIdx.x;
  if (gid >= B_ROWS * T_TICKS) return;
  int b = gid >> 5, t = gid & 31;
  const float* fr = feRaw + ((size_t)b * T_TICKS + t) * 5;
  float mu0 = fr[0] + feB[0], mu1 = fr[1] + feB[1];
  float L00 = softplus_f(fr[2] + feB[2]);
  float L10 = fr[3] + feB[3];
  float L11 = softplus_f(fr[4] + feB[4]);
  const float* ep = eps + ((size_t)t * B_ROWS + b) * 2;
  float e0 = ep[0], e1 = ep[1];
  float z0 = mu0 + L00 * e0;
  float z1 = mu1 + L10 * e0 + L11 * e1;

  float* zs0 = out;
  float* zs1 = out + (size_t)B_ROWS * 2 * T_TICKS;
  float* Ls  = out + (size_t)2 * B_ROWS * 2 * T_TICKS;
  size_t zb = (size_t)b * 2 * T_TICKS + t;
  zs0[zb] = z0; zs0[zb + T_TICKS] = z1;
  zs1[zb] = z0; zs1[zb + T_TICKS] = z1;
  size_t lb = (size_t)b * 4 * T_TICKS + t;
  Ls[lb] = L00;
  Ls[lb + T_TICKS] = 0.f;
  Ls[lb + 2 * T_TICKS] = L10;
  Ls[lb + 3 * T_TICKS] = L11;
}

extern "C" void kernel_launch(void* const* d_in, const int* in_sizes, int n_in,
                              void* d_out, int out_size, void* d_ws, size_t ws_size,
                              hipStream_t stream) {
  const float* x    = (const float*)d_in[0];
  const float* hx   = (const float*)d_in[1];
  const float* eps  = (const float*)d_in[2];
  const float* W_ih = (const float*)d_in[3];
  const float* b_ih = (const float*)d_in[4];
  const float* W_hh = (const float*)d_in[5];
  const float* b_hh = (const float*)d_in[6];
  const float* fe_W = (const float*)d_in[7];
  const float* fe_b = (const float*)d_in[8];
  float* out = (float*)d_out;

  const int NKT_HH = HD / 64;       // 16
  const int NKT_IH = IN_PAD / 64;   // 13
  const int FR_HH = 16 * NKT_HH * 2 * 4;   // 2048 frags
  const int FR_IH = 16 * NKT_IH * 2 * 4;   // 1664 frags

  char* ws = (char*)d_ws;
  bf16* x_bf    = (bf16*)ws;  ws += (size_t)B_ROWS * IN_PAD * 2;
  bf16* hA      = (bf16*)ws;  ws += (size_t)B_ROWS * HD * 2;
  bf16* hB      = (bf16*)ws;  ws += (size_t)B_ROWS * HD * 2;
  bf16* xp_bf   = (bf16*)ws;  ws += (size_t)B_ROWS * HD * 2;
  bf16* pk_hh   = (bf16*)ws;  ws += (size_t)FR_HH * 1024;  // 1024 BYTES per frag
  bf16* pk_ih   = (bf16*)ws;  ws += (size_t)FR_IH * 1024;
  bf16* feP     = (bf16*)ws;  ws += (size_t)32 * 1024;
  float* feRaw  = (float*)ws; ws += (size_t)B_ROWS * T_TICKS * 5 * 4;

  conv_pad_kernel<<<(B_ROWS * IN_PAD + 255) / 256, 256, 0, stream>>>(x, x_bf, B_ROWS, IN_DIM, IN_PAD);
  conv_pad_kernel<<<(B_ROWS * HD + 255) / 256, 256, 0, stream>>>(hx, hA, B_ROWS, HD, HD);
  pack_w<<<(FR_HH * 64 + 255) / 256, 256, 0, stream>>>(W_hh, pk_hh, NKT_HH, HD);
  pack_w<<<(FR_IH * 64 + 255) / 256, 256, 0, stream>>>(W_ih, pk_ih, NKT_IH, IN_DIM);
  pack_fe<<<(32 * 64 + 255) / 256, 256, 0, stream>>>(fe_W, feP);

  // x_proj (+ both biases) -> bf16 : grid 512
  gemm_core<IN_PAD, 0><<<512, 256, 0, stream>>>(
      x_bf, pk_ih, nullptr, b_ih, b_hh,
      nullptr, xp_bf, nullptr, nullptr, -1);

  // ticks: grid 512, fe for h_{t-1} fused on wave0 of ny<4 blocks
  for (int t = 0; t < T_TICKS; ++t) {
    const bf16* hin = (t & 1) ? hB : hA;
    bf16* hout      = (t & 1) ? hA : hB;
    gemm_core<HD, 1><<<512, 256, 0, stream>>>(
        hin, pk_hh, feP, nullptr, nullptr,
        xp_bf, nullptr, hout, feRaw, t - 1);
  }
  // final h is in hA (t=31 odd -> hout = hA)
  fe_last<<<B_ROWS / 4, 256, 0, stream>>>(hA, fe_W, feRaw);
  finish_kernel<<<(B_ROWS * T_TICKS + 255) / 256, 256, 0, stream>>>(feRaw, fe_b, eps, out);
}

// Round 10
// 590.767 us; speedup vs baseline: 1.0689x; 1.0689x over previous
//
#include <hip/hip_runtime.h>
#include <hip/hip_bf16.h>
#include <stdint.h>

#define B_ROWS 4096
#define HD 1024
#define IN_DIM 784
#define IN_PAD 832
#define T_TICKS 32

typedef float f32x4 __attribute__((ext_vector_type(4)));
typedef short short8 __attribute__((ext_vector_type(8)));
typedef __hip_bfloat16 bf16;

// LDS: 2 A-buffers x 8KB (64 rows x 128B, XOR-swizzled via pre-swizzled source)
#define ABUF 8192

__device__ __forceinline__ float b2f(short s) {
  unsigned u = ((unsigned)(unsigned short)s) << 16;
  float f; __builtin_memcpy(&f, &u, 4); return f;
}

__device__ __forceinline__ float softplus_f(float x) {
  if (x > 20.f) return x;
  return log1pf(expf(x));
}

__device__ __forceinline__ float tanh_fast(float x) {
  x = fminf(fmaxf(x, -15.f), 15.f);
  float e = __expf(2.f * x);
  return (e - 1.f) / (e + 1.f);
}

__device__ __forceinline__ void gload_lds16(const void* g, void* l) {
  __builtin_amdgcn_global_load_lds(
      (const __attribute__((address_space(1))) uint32_t*)g,
      (__attribute__((address_space(3))) uint32_t*)l, 16, 0, 0);
}

// ---------- f32 -> bf16 with zero-pad of inner dim ----------
__global__ __launch_bounds__(256) void conv_pad_kernel(
    const float* __restrict__ src, bf16* __restrict__ dst,
    int rows, int scols, int dcols) {
  int idx = blockIdx.x * 256 + threadIdx.x;
  int total = rows * dcols;
  if (idx >= total) return;
  int r = idx / dcols, c = idx - r * dcols;
  float v = (c < scols) ? src[(size_t)r * scols + c] : 0.f;
  dst[idx] = __float2bfloat16(v);
}

// ---------- pack weight (1024 x scols f32) into MFMA B-fragment order ----------
// frag f = ((wnny*nkt + kt)*2 + ks)*4 + n ; each frag = 64 lanes x 16B = 1024B.
// lane(r=lane&15,q=lane>>4): row = wnny*64 + n*16 + r ; k = kt*64 + ks*32 + q*8 .. +8
__global__ __launch_bounds__(256) void pack_w(
    const float* __restrict__ src, bf16* __restrict__ dst,
    int nkt, int scols) {
  int gid = blockIdx.x * 256 + threadIdx.x;
  int lane = gid & 63, f = gid >> 6;
  int total = 16 * nkt * 2 * 4;
  if (f >= total) return;
  int n = f & 3;
  int rest = f >> 2;
  int ks = rest & 1;
  int rest2 = rest >> 1;
  int kt = rest2 % nkt;
  int wnny = rest2 / nkt;
  int r = lane & 15, q = lane >> 4;
  int row = wnny * 64 + n * 16 + r;
  int k0 = kt * 64 + ks * 32 + q * 8;
  short8 v;
#pragma unroll
  for (int e = 0; e < 8; ++e) {
    int c = k0 + e;
    float x = (c < scols) ? src[(size_t)row * scols + c] : 0.f;
    bf16 b = __float2bfloat16(x);
    v[e] = *(short*)&b;
  }
  *(short8*)((char*)dst + (size_t)f * 1024 + lane * 16) = v;
}

// ---------- pack fe_W (5 x 1024 f32 -> 16 padded rows) into fragments ----------
// frag f = kt*2+ks (kt<16); lane(r,q): row=r (zero if >=5), k = kt*64+ks*32+q*8
__global__ __launch_bounds__(256) void pack_fe(
    const float* __restrict__ feW, bf16* __restrict__ dst) {
  int gid = blockIdx.x * 256 + threadIdx.x;
  int lane = gid & 63, f = gid >> 6;
  if (f >= 32) return;
  int ks = f & 1, kt = f >> 1;
  int r = lane & 15, q = lane >> 4;
  int k0 = kt * 64 + ks * 32 + q * 8;
  short8 v;
#pragma unroll
  for (int e = 0; e < 8; ++e) {
    float x = (r < 5) ? feW[(size_t)r * HD + k0 + e] : 0.f;
    bf16 b = __float2bfloat16(x);
    v[e] = *(short*)&b;
  }
  *(short8*)((char*)dst + (size_t)f * 1024 + lane * 16) = v;
}

// ---------- GEMM C = A * B^T, packed-B in registers, A via global_load_lds ----------
// BM=64, BN=128, BK=64, 256 threads (4 waves 2x2, wave tile 32x64). Grid 512.
// Sync: ONLY __syncthreads() per K-step. B(k+1)/A(k+1) issued at the TOP of
// iter k so the barrier's vmcnt drain is covered by the MFMA burst (R9 fix).
// MODE 0: xp_out = bf16(acc + bias1 + bias2)
// MODE 1: outH = bf16(tanh(acc + xp)); fe fused on wave0 of ny<4 blocks.
template<int KDIM, int MODE>
__global__ __launch_bounds__(256) void gemm_core(
    const bf16* __restrict__ A,
    const bf16* __restrict__ Bpk,        // packed B fragments
    const bf16* __restrict__ feP,        // packed fe fragments (MODE 1)
    const float* __restrict__ bias1, const float* __restrict__ bias2,
    const bf16* __restrict__ xp, bf16* __restrict__ xp_out,
    bf16* __restrict__ outH, float* __restrict__ feRaw, int tprev)
{
  __shared__ char lds[2 * ABUF];
  const int tid = threadIdx.x;
  const int lane = tid & 63, w = tid >> 6;
  const int wm = w & 1, wn = w >> 1;
  const int l3 = lane >> 3, l7 = lane & 7;
  const int gcol = l7 ^ l3;               // inverse-swizzled source chunk
  const int r = lane & 15, q = lane >> 4;
  const int r7 = r & 7;
  const int lane16 = lane * 16;
  const int ldaB = KDIM * 2;
  const int NK = KDIM / 64;

  // XCD-chunked bijective swizzle: nwg = 512, 64 per XCD (8 mx x 8 ny)
  int bid = blockIdx.x;
  int v = (bid & 7) * 64 + (bid >> 3);
  const int mx = v >> 3, ny = v & 7;
  const int bm0 = mx * 64, bn0 = ny * 128;

  const bool feW0 = (MODE == 1) && (ny < 4) && (w == 0);

  f32x4 acc[2][4] = {};
  f32x4 acc_fe = {};

  const char* Asrc = (const char*)A + (size_t)(bm0 + l3) * ldaB + gcol * 16;
  const char* Bkt  = (const char*)Bpk + (size_t)(ny * 2 + wn) * NK * 8192;

  short8 Be[8], Bo[8], Bef[2], Bof[2];

#define STAGEA(buf, k)                                                         \
  {                                                                            \
    const char* Ak = Asrc + (size_t)(k) * 128;                                 \
    _Pragma("unroll") for (int j = 0; j < 2; ++j) {                            \
      int iA = w * 2 + j;                                                      \
      gload_lds16(Ak + (size_t)iA * 8 * ldaB, lds + (buf) * ABUF + iA * 1024); \
    }                                                                          \
  }

#define ISSUEB(BS, BSf, k)                                                     \
  {                                                                            \
    const char* bp = Bkt + (size_t)(k) * 8192;                                 \
    _Pragma("unroll") for (int i = 0; i < 8; ++i)                              \
      BS[i] = *(const short8*)(bp + i * 1024 + lane16);                        \
    if (feW0) {                                                                \
      const char* fp = (const char*)feP + (size_t)(k) * 2048;                  \
      BSf[0] = *(const short8*)(fp + lane16);                                  \
      BSf[1] = *(const short8*)(fp + 1024 + lane16);                           \
    }                                                                          \
  }

// iter k: prefetch A(k+1)+B(k+1) FIRST, then compute k from LDS/registers,
// then barrier (its vmcnt drain is covered by the MFMA burst above it).
#define ITER(kp, BSc, BScf, BSn, BSnf)                                         \
  {                                                                            \
    const int _k = (kp);                                                       \
    if (_k + 1 < NK) {                                                         \
      STAGEA((_k + 1) & 1, _k + 1);                                            \
      ISSUEB(BSn, BSnf, _k + 1);                                               \
    }                                                                          \
    const char* lAb = lds + (_k & 1) * ABUF;                                   \
    short8 af[2][2], af_fe[2];                                                 \
    _Pragma("unroll") for (int ks = 0; ks < 2; ++ks) {                         \
      int sw = ((ks * 4 + q) ^ r7) << 4;                                       \
      _Pragma("unroll") for (int m = 0; m < 2; ++m)                            \
        af[ks][m] = *(const short8*)(lAb + (wm * 32 + m * 16 + r) * 128 + sw); \
    }                                                                          \
    if (feW0) {                                                                \
      _Pragma("unroll") for (int ks = 0; ks < 2; ++ks) {                       \
        int sw = ((ks * 4 + q) ^ r7) << 4;                                     \
        af_fe[ks] = *(const short8*)(lAb + (ny * 16 + r) * 128 + sw);          \
      }                                                                        \
    }                                                                          \
    _Pragma("unroll") for (int ks = 0; ks < 2; ++ks)                           \
      _Pragma("unroll") for (int m = 0; m < 2; ++m)                            \
        _Pragma("unroll") for (int n = 0; n < 4; ++n)                          \
          acc[m][n] = __builtin_amdgcn_mfma_f32_16x16x32_bf16(                 \
              af[ks][m], BSc[ks * 4 + n], acc[m][n], 0, 0, 0);                 \
    if (feW0) {                                                                \
      acc_fe = __builtin_amdgcn_mfma_f32_16x16x32_bf16(af_fe[0], BScf[0], acc_fe, 0, 0, 0); \
      acc_fe = __builtin_amdgcn_mfma_f32_16x16x32_bf16(af_fe[1], BScf[1], acc_fe, 0, 0, 0); \
    }                                                                          \
    __syncthreads();                                                           \
  }

  // prologue: stage+issue tile 0 only
  STAGEA(0, 0);
  ISSUEB(Be, Bef, 0);
  __syncthreads();

#pragma unroll
  for (int kt = 0; kt + 1 < NK; kt += 2) {
    ITER(kt,     Be, Bef, Bo, Bof);   // compute even tile from Be, prefetch odd -> Bo
    ITER(kt + 1, Bo, Bof, Be, Bef);   // compute odd tile from Bo, prefetch even -> Be
  }
  if (NK & 1) {
    ITER(NK - 1, Be, Bef, Bo, Bof);   // NK odd: last tile is even-parity -> Be
  }
#undef ITER
#undef ISSUEB
#undef STAGEA

#pragma unroll
  for (int m = 0; m < 2; ++m) {
#pragma unroll
    for (int n = 0; n < 4; ++n) {
      int col = bn0 + wn * 64 + n * 16 + r;
#pragma unroll
      for (int i = 0; i < 4; ++i) {
        int row = bm0 + wm * 32 + m * 16 + q * 4 + i;
        float vv = acc[m][n][i];
        if (MODE == 0) {
          xp_out[(size_t)row * HD + col] = __float2bfloat16(vv + bias1[col] + bias2[col]);
        } else {
          float val = tanh_fast(vv + b2f(*(const short*)&xp[(size_t)row * HD + col]));
          outH[(size_t)row * HD + col] = __float2bfloat16(val);
        }
      }
    }
  }
  if (feW0 && tprev >= 0 && r < 5) {
#pragma unroll
    for (int i = 0; i < 4; ++i) {
      int rowg = bm0 + ny * 16 + q * 4 + i;
      feRaw[((size_t)rowg * T_TICKS + tprev) * 5 + r] = acc_fe[i];
    }
  }
}

// ---------- fe for the last tick: one wave per row, 5 raw dots ----------
__global__ __launch_bounds__(256) void fe_last(
    const bf16* __restrict__ h, const float* __restrict__ feW,
    float* __restrict__ feRaw)
{
  int wid = threadIdx.x >> 6, lane = threadIdx.x & 63;
  int b = blockIdx.x * 4 + wid;
  const bf16* hr = h + (size_t)b * HD + lane * 16;
  short8 hv0 = *(const short8*)hr;
  short8 hv1 = *(const short8*)(hr + 8);
  float hvf[16];
#pragma unroll
  for (int e = 0; e < 8; ++e) { hvf[e] = b2f(hv0[e]); hvf[8 + e] = b2f(hv1[e]); }

  float a0 = 0, a1 = 0, a2 = 0, a3 = 0, a4 = 0;
  int col0 = lane * 16;
#pragma unroll
  for (int e = 0; e < 16; ++e) {
    float hv = hvf[e];
    int col = col0 + e;
    a0 += hv * feW[0 * HD + col];
    a1 += hv * feW[1 * HD + col];
    a2 += hv * feW[2 * HD + col];
    a3 += hv * feW[3 * HD + col];
    a4 += hv * feW[4 * HD + col];
  }
#pragma unroll
  for (int off = 32; off >= 1; off >>= 1) {
    a0 += __shfl_xor(a0, off);
    a1 += __shfl_xor(a1, off);
    a2 += __shfl_xor(a2, off);
    a3 += __shfl_xor(a3, off);
    a4 += __shfl_xor(a4, off);
  }
  if (lane == 0) {
    float* fr = feRaw + ((size_t)b * T_TICKS + (T_TICKS - 1)) * 5;
    fr[0] = a0; fr[1] = a1; fr[2] = a2; fr[3] = a3; fr[4] = a4;
  }
}

// ---------- finish: softplus / z / L for all (b,t) ----------
__global__ __launch_bounds__(256) void finish_kernel(
    const float* __restrict__ feRaw, const float* __restrict__ feB,
    const float* __restrict__ eps, float* __restrict__ out)
{
  int gid = blockIdx.x * 256 + threadIdx.x;
  if (gid >= B_ROWS * T_TICKS) return;
  int b = gid >> 5, t = gid & 31;
  const float* fr = feRaw + ((size_t)b * T_TICKS + t) * 5;
  float mu0 = fr[0] + feB[0], mu1 = fr[1] + feB[1];
  float L00 = softplus_f(fr[2] + feB[2]);
  float L10 = fr[3] + feB[3];
  float L11 = softplus_f(fr[4] + feB[4]);
  const float* ep = eps + ((size_t)t * B_ROWS + b) * 2;
  float e0 = ep[0], e1 = ep[1];
  float z0 = mu0 + L00 * e0;
  float z1 = mu1 + L10 * e0 + L11 * e1;

  float* zs0 = out;
  float* zs1 = out + (size_t)B_ROWS * 2 * T_TICKS;
  float* Ls  = out + (size_t)2 * B_ROWS * 2 * T_TICKS;
  size_t zb = (size_t)b * 2 * T_TICKS + t;
  zs0[zb] = z0; zs0[zb + T_TICKS] = z1;
  zs1[zb] = z0; zs1[zb + T_TICKS] = z1;
  size_t lb = (size_t)b * 4 * T_TICKS + t;
  Ls[lb] = L00;
  Ls[lb + T_TICKS] = 0.f;
  Ls[lb + 2 * T_TICKS] = L10;
  Ls[lb + 3 * T_TICKS] = L11;
}

extern "C" void kernel_launch(void* const* d_in, const int* in_sizes, int n_in,
                              void* d_out, int out_size, void* d_ws, size_t ws_size,
                              hipStream_t stream) {
  const float* x    = (const float*)d_in[0];
  const float* hx   = (const float*)d_in[1];
  const float* eps  = (const float*)d_in[2];
  const float* W_ih = (const float*)d_in[3];
  const float* b_ih = (const float*)d_in[4];
  const float* W_hh = (const float*)d_in[5];
  const float* b_hh = (const float*)d_in[6];
  const float* fe_W = (const float*)d_in[7];
  const float* fe_b = (const float*)d_in[8];
  float* out = (float*)d_out;

  const int NKT_HH = HD / 64;       // 16
  const int NKT_IH = IN_PAD / 64;   // 13
  const int FR_HH = 16 * NKT_HH * 2 * 4;   // 2048 frags
  const int FR_IH = 16 * NKT_IH * 2 * 4;   // 1664 frags

  char* ws = (char*)d_ws;
  bf16* x_bf    = (bf16*)ws;  ws += (size_t)B_ROWS * IN_PAD * 2;
  bf16* hA      = (bf16*)ws;  ws += (size_t)B_ROWS * HD * 2;
  bf16* hB      = (bf16*)ws;  ws += (size_t)B_ROWS * HD * 2;
  bf16* xp_bf   = (bf16*)ws;  ws += (size_t)B_ROWS * HD * 2;
  bf16* pk_hh   = (bf16*)ws;  ws += (size_t)FR_HH * 1024;  // 1024 BYTES per frag
  bf16* pk_ih   = (bf16*)ws;  ws += (size_t)FR_IH * 1024;
  bf16* feP     = (bf16*)ws;  ws += (size_t)32 * 1024;
  float* feRaw  = (float*)ws; ws += (size_t)B_ROWS * T_TICKS * 5 * 4;

  conv_pad_kernel<<<(B_ROWS * IN_PAD + 255) / 256, 256, 0, stream>>>(x, x_bf, B_ROWS, IN_DIM, IN_PAD);
  conv_pad_kernel<<<(B_ROWS * HD + 255) / 256, 256, 0, stream>>>(hx, hA, B_ROWS, HD, HD);
  pack_w<<<(FR_HH * 64 + 255) / 256, 256, 0, stream>>>(W_hh, pk_hh, NKT_HH, HD);
  pack_w<<<(FR_IH * 64 + 255) / 256, 256, 0, stream>>>(W_ih, pk_ih, NKT_IH, IN_DIM);
  pack_fe<<<(32 * 64 + 255) / 256, 256, 0, stream>>>(fe_W, feP);

  // x_proj (+ both biases) -> bf16 : grid 512
  gemm_core<IN_PAD, 0><<<512, 256, 0, stream>>>(
      x_bf, pk_ih, nullptr, b_ih, b_hh,
      nullptr, xp_bf, nullptr, nullptr, -1);

  // ticks: grid 512, fe for h_{t-1} fused on wave0 of ny<4 blocks
  for (int t = 0; t < T_TICKS; ++t) {
    const bf16* hin = (t & 1) ? hB : hA;
    bf16* hout      = (t & 1) ? hA : hB;
    gemm_core<HD, 1><<<512, 256, 0, stream>>>(
        hin, pk_hh, feP, nullptr, nullptr,
        xp_bf, nullptr, hout, feRaw, t - 1);
  }
  // final h is in hA (t=31 odd -> hout = hA)
  fe_last<<<B_ROWS / 4, 256, 0, stream>>>(hA, fe_W, feRaw);
  finish_kernel<<<(B_ROWS * T_TICKS + 255) / 256, 256, 0, stream>>>(feRaw, fe_b, eps, out);
}